// Round 12
// baseline (713.039 us; speedup 1.0000x reference)
//
#include <hip/hip_runtime.h>
#include <hip/hip_bf16.h>
#include <cstdint>
#include <cstddef>

// Problem dims
#define M_ROWS   4096     // B*T
#define N_VOCAB  32000    // V
#define K_DIM    512      // D
#define S_DIM    400
#define CV_DIM   600
#define OUT_PITCH 32600   // V + CV
#define PAD_IDX  1

typedef __attribute__((ext_vector_type(8))) short short8;
typedef __attribute__((ext_vector_type(8))) unsigned short ushort8;
typedef __attribute__((ext_vector_type(4))) float f32x4;

// ws layout
#define WB_OFF   0ull                       // W bf16: 32,768,000 B
#define HB_OFF   32768000ull                // hidden bf16: 4,194,304 B
#define COPYG_OFF 36962304ull
#define RSUM_OFF  36978688ull
#define SSCALE_OFF 36995072ull
#define SRCID_OFF 37011456ull               // 51,200 B
#define EB_OFF    37062656ull               // bf16 exp intermediate: 262,144,000 B
#define WS_NEED_BF16 (EB_OFF + 262144000ull)

__device__ inline void gload_lds16(const void* g, void* l) {
  __builtin_amdgcn_global_load_lds(
      (const __attribute__((address_space(1))) unsigned int*)g,
      (__attribute__((address_space(3))) unsigned int*)l, 16, 0, 0);
}

__device__ inline unsigned short f32_to_bf16_rn(float f) {
  unsigned u = __float_as_uint(f);
  u += 0x7FFFu + ((u >> 16) & 1u);
  return (unsigned short)(u >> 16);
}
__device__ inline float bf16_to_f32(unsigned short h) {
  return __uint_as_float((unsigned)h << 16);
}

// ---------- K1a: fp32 -> bf16 conversion (W only) ----------
__global__ void cvt_kernel(const float4* __restrict__ in, ushort4* __restrict__ out, unsigned n4) {
  unsigned stride = gridDim.x * blockDim.x;
  for (unsigned i = blockIdx.x * blockDim.x + threadIdx.x; i < n4; i += stride) {
    float4 v = in[i];
    ushort4 o;
    o.x = f32_to_bf16_rn(v.x);
    o.y = f32_to_bf16_rn(v.y);
    o.z = f32_to_bf16_rn(v.z);
    o.w = f32_to_bf16_rn(v.w);
    out[i] = o;
  }
}

// ---------- K1b: copy gate + hidden->bf16 (fused; one wave per row) ----------
__global__ void copygate_cvt_kernel(const float* __restrict__ hidden,
                                    const float* __restrict__ w_copy,
                                    const float* __restrict__ b_copy,
                                    float* __restrict__ copyg,
                                    unsigned short* __restrict__ Hb) {
  unsigned gw = (blockIdx.x * blockDim.x + threadIdx.x) >> 6;   // row
  unsigned lane = threadIdx.x & 63u;
  if (gw >= M_ROWS) return;
  const float4* h4 = (const float4*)(hidden + (size_t)gw * K_DIM);
  const float4* w4 = (const float4*)w_copy;
  float4 a0 = h4[lane * 2 + 0], w0 = w4[lane * 2 + 0];
  float4 a1 = h4[lane * 2 + 1], w1 = w4[lane * 2 + 1];
  float dot = a0.x * w0.x + a0.y * w0.y + a0.z * w0.z + a0.w * w0.w
            + a1.x * w1.x + a1.y * w1.y + a1.z * w1.z + a1.w * w1.w;
  ushort8 hb;
  hb[0] = f32_to_bf16_rn(a0.x); hb[1] = f32_to_bf16_rn(a0.y);
  hb[2] = f32_to_bf16_rn(a0.z); hb[3] = f32_to_bf16_rn(a0.w);
  hb[4] = f32_to_bf16_rn(a1.x); hb[5] = f32_to_bf16_rn(a1.y);
  hb[6] = f32_to_bf16_rn(a1.z); hb[7] = f32_to_bf16_rn(a1.w);
  *(ushort8*)(Hb + (size_t)gw * K_DIM + lane * 8u) = hb;
  #pragma unroll
  for (int mask = 1; mask < 64; mask <<= 1) dot += __shfl_xor(dot, mask);
  if (lane == 0) copyg[gw] = 1.f / (1.f + __expf(-(dot + b_copy[0])));
}

// ---------- K1c: recover src_ids from one-hot src_map ----------
__global__ void srcids_kernel(const float* __restrict__ src_map, int* __restrict__ src_ids) {
  unsigned pos = (blockIdx.x * blockDim.x + threadIdx.x) >> 6;
  unsigned lane = threadIdx.x & 63u;
  if (pos >= 32 * S_DIM) return;
  const float* row = src_map + (size_t)pos * CV_DIM;
  int found = 1 << 30;
  for (int v = lane; v < CV_DIM; v += 64)
    if (row[v] > 0.5f) found = v;
  #pragma unroll
  for (int mask = 1; mask < 64; mask <<= 1) {
    int o = __shfl_xor(found, mask);
    found = found < o ? found : o;
  }
  if (lane == 0) src_ids[pos] = found;
}

// ---------- K2: persistent-A zero-barrier bf16 MFMA GEMM + exp epilogue ----------
// 256 blocks (1/CU), 8 waves (2M x 4N). Block loads its 128-row A slab into
// LDS ONCE (128 KB, swizzled), then loops its XCD-locked B column range
// (bid&7 -> ~4 MB B range, L2-resident) with ZERO barriers: A frags from
// read-only LDS, B frags loaded global->register (16 rows x 64 B lines),
// swapped-operand MFMA, register-direct ushort4 bf16 stores (R7-proven).
template<int BF16OUT>
__global__ __launch_bounds__(512, 1)
void gemm_exp_kernel(const unsigned short* __restrict__ A,
                     const unsigned short* __restrict__ B,
                     const float* __restrict__ bias,
                     float* __restrict__ out,
                     unsigned short* __restrict__ Eb,
                     float* __restrict__ row_sum) {
  __shared__ unsigned short As[128 * 512];   // 128 KB, [row][chunk^(row&7)][8]

  unsigned bid = blockIdx.x;
  unsigned nrange = bid & 7u;                // XCD-locked B range
  unsigned slab = bid >> 3;                  // 0..31
  unsigned m0 = slab * 128u;
  unsigned t0 = (nrange * 125u) >> 3;        // ragged 15/16-tile ranges, sum=125
  unsigned t1 = ((nrange + 1u) * 125u) >> 3;

  unsigned tid = threadIdx.x;
  unsigned lane = tid & 63u;
  unsigned wid = tid >> 6;
  unsigned wm = wid >> 2, wn = wid & 3u;     // 2 x 4 wave grid, 64x64 per wave
  unsigned lr = lane >> 4, lc = lane & 15u;

  // ---- A slab -> LDS once (inverse-swizzled source, linear dest) ----
  #pragma unroll
  for (unsigned i = 0; i < 16; ++i) {
    unsigned u = i * 512u + tid;             // 0..8191 16B-units
    unsigned row = u >> 6;                   // 0..127 (64 chunks/row)
    unsigned c = u & 63u;
    unsigned cs = c ^ (row & 7u);
    gload_lds16(A + (size_t)(m0 + row) * K_DIM + cs * 8u, (char*)As + (size_t)u * 16u);
  }
  asm volatile("s_waitcnt vmcnt(0)" ::: "memory");
  __syncthreads();                            // the ONLY barrier

  // A fragment read offsets: row = wm*64+m*16+lc; global chunk g = kt*8+ks*4+lr;
  // LDS chunk = g ^ (lc&7)  (low 3 bits only: kt*8 untouched)
  unsigned arow[4];
  #pragma unroll
  for (int m = 0; m < 4; ++m) arow[m] = (wm * 64u + m * 16u + lc) * 512u;
  const unsigned chk0 = ((0u * 4u + lr) ^ (lc & 7u)) * 8u;   // ks=0
  const unsigned chk1 = ((1u * 4u + lr) ^ (lc & 7u)) * 8u;   // ks=1

  for (unsigned t = t0; t < t1; ++t) {
    unsigned n0 = t * 256u;
    const unsigned short* Bn[4];
    #pragma unroll
    for (int n = 0; n < 4; ++n)
      Bn[n] = B + (size_t)(n0 + wn * 64u + n * 16u + lc) * K_DIM + lr * 8u;

    f32x4 acc[4][4] = {};
    #pragma unroll
    for (unsigned kt = 0; kt < 8; ++kt) {
      short8 af[4][2], bf[4][2];
      #pragma unroll
      for (int n = 0; n < 4; ++n) {
        bf[n][0] = *(const short8*)(Bn[n] + kt * 64u);
        bf[n][1] = *(const short8*)(Bn[n] + kt * 64u + 32u);
      }
      #pragma unroll
      for (int m = 0; m < 4; ++m) {
        af[m][0] = *(const short8*)&As[arow[m] + kt * 64u + chk0];
        af[m][1] = *(const short8*)&As[arow[m] + kt * 64u + chk1];
      }
      // swapped operands: lane holds 4 consecutive output columns
      #pragma unroll
      for (int ks = 0; ks < 2; ++ks)
        #pragma unroll
        for (int m = 0; m < 4; ++m)
          #pragma unroll
          for (int n = 0; n < 4; ++n)
            acc[m][n] = __builtin_amdgcn_mfma_f32_16x16x32_bf16(
                ks ? bf[n][1] : bf[n][0], ks ? af[m][1] : af[m][0], acc[m][n], 0, 0, 0);
    }

    // epilogue: acc[m][n][j] = logit(row = m0+wm*64+m*16+lc, col = n0+wn*64+n*16+lr*4+j)
    float4 bv4[4];
    #pragma unroll
    for (int n = 0; n < 4; ++n)
      bv4[n] = *(const float4*)&bias[n0 + wn * 64u + n * 16u + lr * 4u];

    if (BF16OUT) {
      #pragma unroll
      for (int m = 0; m < 4; ++m) {
        unsigned grow = m0 + wm * 64u + m * 16u + lc;
        unsigned short* rowp = Eb + (size_t)grow * N_VOCAB;
        #pragma unroll
        for (int n = 0; n < 4; ++n) {
          unsigned gcol = n0 + wn * 64u + n * 16u + lr * 4u;
          float e0 = (gcol + 0u == PAD_IDX) ? 0.f : __expf(acc[m][n][0] + bv4[n].x);
          float e1 = (gcol + 1u == PAD_IDX) ? 0.f : __expf(acc[m][n][1] + bv4[n].y);
          float e2 = (gcol + 2u == PAD_IDX) ? 0.f : __expf(acc[m][n][2] + bv4[n].z);
          float e3 = (gcol + 3u == PAD_IDX) ? 0.f : __expf(acc[m][n][3] + bv4[n].w);
          ushort4 o;
          o.x = f32_to_bf16_rn(e0); o.y = f32_to_bf16_rn(e1);
          o.z = f32_to_bf16_rn(e2); o.w = f32_to_bf16_rn(e3);
          *(ushort4*)(rowp + gcol) = o;
        }
      }
    } else {
      // fallback: fp32 float4 stores + atomic row sums
      #pragma unroll
      for (int m = 0; m < 4; ++m) {
        unsigned grow = m0 + wm * 64u + m * 16u + lc;
        float rs = 0.f;
        #pragma unroll
        for (int n = 0; n < 4; ++n) {
          unsigned gcol = n0 + wn * 64u + n * 16u + lr * 4u;
          float4 e;
          e.x = (gcol + 0u == PAD_IDX) ? 0.f : __expf(acc[m][n][0] + bv4[n].x);
          e.y = (gcol + 1u == PAD_IDX) ? 0.f : __expf(acc[m][n][1] + bv4[n].y);
          e.z = (gcol + 2u == PAD_IDX) ? 0.f : __expf(acc[m][n][2] + bv4[n].z);
          e.w = (gcol + 3u == PAD_IDX) ? 0.f : __expf(acc[m][n][3] + bv4[n].w);
          *(float4*)(out + (size_t)grow * OUT_PITCH + gcol) = e;
          rs += e.x + e.y + e.z + e.w;
        }
        rs += __shfl_xor(rs, 16);
        rs += __shfl_xor(rs, 32);
        if (lr == 0) atomicAdd(&row_sum[grow], rs);
      }
    }
  }
}

// ---------- K3: per-row sum + scale: out = Eb * (1-gate)/sum (R8-proven) ----------
__global__ __launch_bounds__(256)
void norm_scale_kernel(const unsigned short* __restrict__ Eb,
                       const float* __restrict__ copyg,
                       float* __restrict__ out) {
  unsigned r = blockIdx.x;
  unsigned tid = threadIdx.x;
  const ushort8* src = (const ushort8*)(Eb + (size_t)r * N_VOCAB);   // 4000 chunks
  ushort8 v[16];
  float lsum = 0.f;
  #pragma unroll
  for (int i = 0; i < 16; ++i) {
    unsigned c = (unsigned)i * 256u + tid;
    if (c < 4000u) {
      v[i] = src[c];
      #pragma unroll
      for (int k = 0; k < 8; ++k) lsum += bf16_to_f32(v[i][k]);
    }
  }
  #pragma unroll
  for (int mask = 1; mask < 64; mask <<= 1) lsum += __shfl_xor(lsum, mask);
  __shared__ float wsum[4];
  if ((tid & 63u) == 0) wsum[tid >> 6] = lsum;
  __syncthreads();
  float s = (1.f - copyg[r]) / (wsum[0] + wsum[1] + wsum[2] + wsum[3]);
  float* dst = out + (size_t)r * OUT_PITCH;
  #pragma unroll
  for (int i = 0; i < 16; ++i) {
    unsigned c = (unsigned)i * 256u + tid;
    if (c < 4000u) {
      float4 lo, hi;
      lo.x = bf16_to_f32(v[i][0]) * s; lo.y = bf16_to_f32(v[i][1]) * s;
      lo.z = bf16_to_f32(v[i][2]) * s; lo.w = bf16_to_f32(v[i][3]) * s;
      hi.x = bf16_to_f32(v[i][4]) * s; hi.y = bf16_to_f32(v[i][5]) * s;
      hi.z = bf16_to_f32(v[i][6]) * s; hi.w = bf16_to_f32(v[i][7]) * s;
      float4* o = (float4*)(dst + c * 8u);
      o[0] = lo; o[1] = hi;
    }
  }
}

// ---------- fallback-path kernels ----------
__global__ void finalize_kernel(const float* __restrict__ row_sum, const float* __restrict__ copyg,
                                float* __restrict__ sscale) {
  unsigned r = blockIdx.x * blockDim.x + threadIdx.x;
  if (r < M_ROWS) sscale[r] = (1.f - copyg[r]) / row_sum[r];
}

__global__ void scale_kernel(float4* __restrict__ out, const float* __restrict__ sscale) {
  const unsigned total = M_ROWS * (N_VOCAB / 4);
  unsigned stride = gridDim.x * blockDim.x;
  for (unsigned i = blockIdx.x * blockDim.x + threadIdx.x; i < total; i += stride) {
    unsigned r = i / (N_VOCAB / 4);
    unsigned c = i % (N_VOCAB / 4);
    float s = sscale[r];
    float4 v = out[(size_t)r * (OUT_PITCH / 4) + c];
    v.x *= s; v.y *= s; v.z *= s; v.w *= s;
    out[(size_t)r * (OUT_PITCH / 4) + c] = v;
  }
}

// ---------- K4: copy branch scatter ----------
__global__ void copyprob_kernel(const float* __restrict__ attn, const int* __restrict__ src_ids,
                                const float* __restrict__ copyg, float* __restrict__ out) {
  unsigned r = blockIdx.x;
  unsigned tid = threadIdx.x;
  __shared__ float cp[CV_DIM];
  for (unsigned v = tid; v < CV_DIM; v += 128) cp[v] = 0.f;
  __syncthreads();
  unsigned batch = r >> 7;
  float g = copyg[r];
  for (unsigned s = tid; s < S_DIM; s += 128) {
    float a = attn[(size_t)r * S_DIM + s] * g;
    atomicAdd(&cp[src_ids[batch * S_DIM + s]], a);
  }
  __syncthreads();
  for (unsigned v = tid; v < CV_DIM; v += 128)
    out[(size_t)r * OUT_PITCH + N_VOCAB + v] = cp[v];
}

extern "C" void kernel_launch(void* const* d_in, const int* in_sizes, int n_in,
                              void* d_out, int out_size, void* d_ws, size_t ws_size,
                              hipStream_t stream) {
  const float* hidden    = (const float*)d_in[0];
  const float* copy_attn = (const float*)d_in[1];
  const float* src_map   = (const float*)d_in[2];
  const float* W         = (const float*)d_in[3];
  const float* bias      = (const float*)d_in[4];
  const float* w_copy    = (const float*)d_in[5];
  const float* b_copy    = (const float*)d_in[6];
  float* out = (float*)d_out;

  char* ws = (char*)d_ws;
  unsigned short* Wb = (unsigned short*)(ws + WB_OFF);
  unsigned short* Hb = (unsigned short*)(ws + HB_OFF);
  float* copyg   = (float*)(ws + COPYG_OFF);
  float* row_sum = (float*)(ws + RSUM_OFF);
  float* sscale  = (float*)(ws + SSCALE_OFF);
  int*   src_ids = (int*)(ws + SRCID_OFF);
  unsigned short* Eb = (unsigned short*)(ws + EB_OFF);

  const bool bf16_path = (ws_size >= WS_NEED_BF16);

  cvt_kernel<<<2048, 256, 0, stream>>>((const float4*)W, (ushort4*)Wb,
                                       (unsigned)(N_VOCAB * K_DIM / 4));
  copygate_cvt_kernel<<<M_ROWS / 4, 256, 0, stream>>>(hidden, w_copy, b_copy, copyg, Hb);
  srcids_kernel<<<(32 * S_DIM) / 4, 256, 0, stream>>>(src_map, src_ids);

  // main GEMM: 256 persistent blocks (32 slabs x 8 XCD-locked n-ranges)
  if (bf16_path) {
    gemm_exp_kernel<1><<<256, 512, 0, stream>>>(Hb, Wb, bias, out, Eb, row_sum);
    norm_scale_kernel<<<M_ROWS, 256, 0, stream>>>(Eb, copyg, out);
  } else {
    hipMemsetAsync(row_sum, 0, M_ROWS * sizeof(float), stream);
    gemm_exp_kernel<0><<<256, 512, 0, stream>>>(Hb, Wb, bias, out, Eb, row_sum);
    finalize_kernel<<<(M_ROWS + 255) / 256, 256, 0, stream>>>(row_sum, copyg, sscale);
    scale_kernel<<<4096, 256, 0, stream>>>((float4*)out, sscale);
  }

  copyprob_kernel<<<M_ROWS, 128, 0, stream>>>(copy_attn, src_ids, copyg, out);
}

// Round 13
// 363.549 us; speedup vs baseline: 1.9613x; 1.9613x over previous
//
#include <hip/hip_runtime.h>
#include <hip/hip_bf16.h>
#include <hip/hip_fp8.h>
#include <cstdint>
#include <cstddef>

// Problem dims
#define M_ROWS   4096     // B*T
#define N_VOCAB  32000    // V
#define K_DIM    512      // D
#define S_DIM    400
#define CV_DIM   600
#define OUT_PITCH 32600   // V + CV
#define PAD_IDX  1

typedef __attribute__((ext_vector_type(8))) short short8;
typedef __attribute__((ext_vector_type(8))) unsigned short ushort8;
typedef __attribute__((ext_vector_type(4))) float f32x4;
typedef long long i64;

// ws layout (fp8 inputs + bf16 exp intermediate)
#define W8_OFF   0ull                        // W fp8: 16,384,000 B
#define H8_OFF   16384000ull                 // hidden fp8: 2,097,152 B
#define COPYG_OFF 18481152ull
#define RSUM_OFF  18497536ull
#define SSCALE_OFF 18513920ull
#define SRCID_OFF 18530304ull                // 51,200 B
#define EB_OFF    18581504ull                // bf16 exp intermediate: 262,144,000 B
#define WS_NEED   (EB_OFF + 262144000ull)

__device__ inline void gload_lds16(const void* g, void* l) {
  __builtin_amdgcn_global_load_lds(
      (const __attribute__((address_space(1))) unsigned int*)g,
      (__attribute__((address_space(3))) unsigned int*)l, 16, 0, 0);
}

__device__ inline unsigned short f32_to_bf16_rn(float f) {
  unsigned u = __float_as_uint(f);
  u += 0x7FFFu + ((u >> 16) & 1u);
  return (unsigned short)(u >> 16);
}
__device__ inline float bf16_to_f32(unsigned short h) {
  return __uint_as_float((unsigned)h << 16);
}
__device__ inline unsigned f32_to_fp8(float f) {
  __hip_fp8_e4m3 q(f);
  return (unsigned)(unsigned char)q.__x;
}

// ---------- K1a: fp32 -> fp8 conversion (W), packed 4/thread ----------
__global__ void cvt8_kernel(const float4* __restrict__ in, unsigned* __restrict__ out, unsigned n4) {
  unsigned stride = gridDim.x * blockDim.x;
  for (unsigned i = blockIdx.x * blockDim.x + threadIdx.x; i < n4; i += stride) {
    float4 v = in[i];
    out[i] = f32_to_fp8(v.x) | (f32_to_fp8(v.y) << 8)
           | (f32_to_fp8(v.z) << 16) | (f32_to_fp8(v.w) << 24);
  }
}

// ---------- K1b: copy gate + hidden->fp8 (fused; one wave per row) ----------
__global__ void copygate_cvt_kernel(const float* __restrict__ hidden,
                                    const float* __restrict__ w_copy,
                                    const float* __restrict__ b_copy,
                                    float* __restrict__ copyg,
                                    unsigned char* __restrict__ H8) {
  unsigned gw = (blockIdx.x * blockDim.x + threadIdx.x) >> 6;   // row
  unsigned lane = threadIdx.x & 63u;
  if (gw >= M_ROWS) return;
  const float4* h4 = (const float4*)(hidden + (size_t)gw * K_DIM);
  const float4* w4 = (const float4*)w_copy;
  float4 a0 = h4[lane * 2 + 0], w0 = w4[lane * 2 + 0];
  float4 a1 = h4[lane * 2 + 1], w1 = w4[lane * 2 + 1];
  float dot = a0.x * w0.x + a0.y * w0.y + a0.z * w0.z + a0.w * w0.w
            + a1.x * w1.x + a1.y * w1.y + a1.z * w1.z + a1.w * w1.w;
  unsigned lo = f32_to_fp8(a0.x) | (f32_to_fp8(a0.y) << 8)
              | (f32_to_fp8(a0.z) << 16) | (f32_to_fp8(a0.w) << 24);
  unsigned hi = f32_to_fp8(a1.x) | (f32_to_fp8(a1.y) << 8)
              | (f32_to_fp8(a1.z) << 16) | (f32_to_fp8(a1.w) << 24);
  uint2 pk; pk.x = lo; pk.y = hi;
  *(uint2*)(H8 + (size_t)gw * K_DIM + lane * 8u) = pk;
  #pragma unroll
  for (int mask = 1; mask < 64; mask <<= 1) dot += __shfl_xor(dot, mask);
  if (lane == 0) copyg[gw] = 1.f / (1.f + __expf(-(dot + b_copy[0])));
}

// ---------- K1c: recover src_ids from one-hot src_map ----------
__global__ void srcids_kernel(const float* __restrict__ src_map, int* __restrict__ src_ids) {
  unsigned pos = (blockIdx.x * blockDim.x + threadIdx.x) >> 6;
  unsigned lane = threadIdx.x & 63u;
  if (pos >= 32 * S_DIM) return;
  const float* row = src_map + (size_t)pos * CV_DIM;
  int found = 1 << 30;
  for (int v = lane; v < CV_DIM; v += 64)
    if (row[v] > 0.5f) found = v;
  #pragma unroll
  for (int mask = 1; mask < 64; mask <<= 1) {
    int o = __shfl_xor(found, mask);
    found = found < o ? found : o;
  }
  if (lane == 0) src_ids[pos] = found;
}

// ---------- K2: 256x128 fp8 MFMA GEMM, BK=128 + exp epilogue (bf16 out) ----------
// 8 waves (4M x 2N), 64x64/wave, BK=128 -> only 4 K-steps (4 barrier drains).
// 48 KB LDS (As 32K | Bs 16K), rows = 128 B = 8 x 16B chunks, XOR-(row&7)
// swizzle (same proven 0-conflict geometry as bf16 version). 2 blocks/CU.
// mfma_f32_16x16x32_fp8_fp8, swapped operands: lane holds 4 consecutive
// output cols -> register-direct packed stores.
template<int BF16OUT>
__global__ __launch_bounds__(512, 2)
void gemm_exp_kernel(const unsigned char* __restrict__ A,
                     const unsigned char* __restrict__ B,
                     const float* __restrict__ bias,
                     float* __restrict__ out,
                     unsigned short* __restrict__ Eb,
                     float* __restrict__ row_sum) {
  __shared__ unsigned char smem[49152];      // As 32 KB | Bs 16 KB
  unsigned char* As = smem;
  unsigned char* Bs = smem + 32768;

  unsigned bid = blockIdx.x;
  // reuse-aware bijective map over 4000 blocks (16 mt x 250 nt)
  unsigned xcd = bid & 7u, local = bid >> 3;      // local 0..499
  unsigned slab = xcd >> 1, half = xcd & 1u;
  unsigned nt = half * 125u + (local >> 2);
  unsigned mt = slab * 4u + (local & 3u);
  unsigned m0 = mt * 256u, n0 = nt * 128u;

  unsigned tid = threadIdx.x;
  unsigned lane = tid & 63u;
  unsigned wid = tid >> 6;
  unsigned wm = wid >> 1, wn = wid & 1u;     // 4 x 2 wave grid, 64x64 per wave
  unsigned lr = lane >> 4, lc = lane & 15u;

  // staging: A 2048 16B-units, B 1024; unit u -> row u>>3, lds chunk u&7,
  // source chunk (u&7)^(row&7). Row = 128 fp8 = 128 B.
  const unsigned char* Asrc[4];
  const unsigned char* Bsrc[2];
  unsigned dstA[4], dstB[2];
  #pragma unroll
  for (unsigned i = 0; i < 4; ++i) {
    unsigned u = i * 512u + tid;
    unsigned rr = u >> 3;                        // 0..255
    unsigned ch = (u & 7u) ^ (rr & 7u);
    dstA[i] = u * 16u;
    Asrc[i] = A + (size_t)(m0 + rr) * K_DIM + ch * 16u;
  }
  #pragma unroll
  for (unsigned i = 0; i < 2; ++i) {
    unsigned u = i * 512u + tid;
    unsigned rr = u >> 3;                        // 0..127
    unsigned ch = (u & 7u) ^ (rr & 7u);
    dstB[i] = u * 16u;
    Bsrc[i] = B + (size_t)(n0 + rr) * K_DIM + ch * 16u;
  }
  // fragment read bases: row byte base + swizzle key
  unsigned abase[4], akey[4], bbase[4], bkey[4];
  #pragma unroll
  for (int m = 0; m < 4; ++m) {
    unsigned r = wm * 64u + m * 16u + lc;
    abase[m] = r * 128u; akey[m] = r & 7u;
  }
  #pragma unroll
  for (int n = 0; n < 4; ++n) {
    unsigned r = wn * 64u + n * 16u + lc;
    bbase[n] = r * 128u; bkey[n] = r & 7u;
  }
  const unsigned hsel = (lr & 1u) * 8u;          // 8B half within 16B chunk

  f32x4 acc[4][4] = {};

  for (unsigned kt = 0; kt < 4; ++kt) {          // BK=128: 4 K-steps only
    unsigned k0 = kt * 128u;
    #pragma unroll
    for (unsigned i = 0; i < 4; ++i)
      gload_lds16(Asrc[i] + k0, As + dstA[i]);
    #pragma unroll
    for (unsigned i = 0; i < 2; ++i)
      gload_lds16(Bsrc[i] + k0, Bs + dstB[i]);
    __syncthreads();   // compiler emits vmcnt(0) drain before barrier
    #pragma unroll
    for (unsigned ks = 0; ks < 4; ++ks) {        // k = ks*32 .. +32
      unsigned h = ks * 2u + (lr >> 1);          // 16B chunk index 0..7
      i64 av[4], bv[4];
      #pragma unroll
      for (int m = 0; m < 4; ++m)
        av[m] = *(const i64*)(As + abase[m] + ((h ^ akey[m]) * 16u) + hsel);
      #pragma unroll
      for (int n = 0; n < 4; ++n)
        bv[n] = *(const i64*)(Bs + bbase[n] + ((h ^ bkey[n]) * 16u) + hsel);
      #pragma unroll
      for (int m = 0; m < 4; ++m)
        #pragma unroll
        for (int n = 0; n < 4; ++n)
          acc[m][n] = __builtin_amdgcn_mfma_f32_16x16x32_fp8_fp8(bv[n], av[m],
                                                                 acc[m][n], 0, 0, 0);
    }
    __syncthreads();
  }

  // epilogue: acc[m][n][j] = logit(row = m0+wm*64+m*16+lc, col = n0+wn*64+n*16+lr*4+j)
  float4 bv4[4];
  #pragma unroll
  for (int n = 0; n < 4; ++n)
    bv4[n] = *(const float4*)&bias[n0 + wn * 64u + n * 16u + lr * 4u];

  if (BF16OUT) {
    #pragma unroll
    for (int m = 0; m < 4; ++m) {
      unsigned grow = m0 + wm * 64u + m * 16u + lc;
      unsigned short* rowp = Eb + (size_t)grow * N_VOCAB;
      #pragma unroll
      for (int n = 0; n < 4; ++n) {
        unsigned gcol = n0 + wn * 64u + n * 16u + lr * 4u;
        float e0 = (gcol + 0u == PAD_IDX) ? 0.f : __expf(acc[m][n][0] + bv4[n].x);
        float e1 = (gcol + 1u == PAD_IDX) ? 0.f : __expf(acc[m][n][1] + bv4[n].y);
        float e2 = (gcol + 2u == PAD_IDX) ? 0.f : __expf(acc[m][n][2] + bv4[n].z);
        float e3 = (gcol + 3u == PAD_IDX) ? 0.f : __expf(acc[m][n][3] + bv4[n].w);
        ushort4 o;
        o.x = f32_to_bf16_rn(e0); o.y = f32_to_bf16_rn(e1);
        o.z = f32_to_bf16_rn(e2); o.w = f32_to_bf16_rn(e3);
        *(ushort4*)(rowp + gcol) = o;
      }
    }
  } else {
    // fallback: fp32 float4 stores + atomic row sums
    #pragma unroll
    for (int m = 0; m < 4; ++m) {
      unsigned grow = m0 + wm * 64u + m * 16u + lc;
      float rs = 0.f;
      #pragma unroll
      for (int n = 0; n < 4; ++n) {
        unsigned gcol = n0 + wn * 64u + n * 16u + lr * 4u;
        float4 e;
        e.x = (gcol + 0u == PAD_IDX) ? 0.f : __expf(acc[m][n][0] + bv4[n].x);
        e.y = (gcol + 1u == PAD_IDX) ? 0.f : __expf(acc[m][n][1] + bv4[n].y);
        e.z = (gcol + 2u == PAD_IDX) ? 0.f : __expf(acc[m][n][2] + bv4[n].z);
        e.w = (gcol + 3u == PAD_IDX) ? 0.f : __expf(acc[m][n][3] + bv4[n].w);
        *(float4*)(out + (size_t)grow * OUT_PITCH + gcol) = e;
        rs += e.x + e.y + e.z + e.w;
      }
      rs += __shfl_xor(rs, 16);
      rs += __shfl_xor(rs, 32);
      if (lr == 0) atomicAdd(&row_sum[grow], rs);
    }
  }
}

// ---------- K3: per-row sum + scale: out = Eb * (1-gate)/sum (R8-proven) ----------
__global__ __launch_bounds__(256)
void norm_scale_kernel(const unsigned short* __restrict__ Eb,
                       const float* __restrict__ copyg,
                       float* __restrict__ out) {
  unsigned r = blockIdx.x;
  unsigned tid = threadIdx.x;
  const ushort8* src = (const ushort8*)(Eb + (size_t)r * N_VOCAB);   // 4000 chunks
  ushort8 v[16];
  float lsum = 0.f;
  #pragma unroll
  for (int i = 0; i < 16; ++i) {
    unsigned c = (unsigned)i * 256u + tid;
    if (c < 4000u) {
      v[i] = src[c];
      #pragma unroll
      for (int k = 0; k < 8; ++k) lsum += bf16_to_f32(v[i][k]);
    }
  }
  #pragma unroll
  for (int mask = 1; mask < 64; mask <<= 1) lsum += __shfl_xor(lsum, mask);
  __shared__ float wsum[4];
  if ((tid & 63u) == 0) wsum[tid >> 6] = lsum;
  __syncthreads();
  float s = (1.f - copyg[r]) / (wsum[0] + wsum[1] + wsum[2] + wsum[3]);
  float* dst = out + (size_t)r * OUT_PITCH;
  #pragma unroll
  for (int i = 0; i < 16; ++i) {
    unsigned c = (unsigned)i * 256u + tid;
    if (c < 4000u) {
      float4 lo, hi;
      lo.x = bf16_to_f32(v[i][0]) * s; lo.y = bf16_to_f32(v[i][1]) * s;
      lo.z = bf16_to_f32(v[i][2]) * s; lo.w = bf16_to_f32(v[i][3]) * s;
      hi.x = bf16_to_f32(v[i][4]) * s; hi.y = bf16_to_f32(v[i][5]) * s;
      hi.z = bf16_to_f32(v[i][6]) * s; hi.w = bf16_to_f32(v[i][7]) * s;
      float4* o = (float4*)(dst + c * 8u);
      o[0] = lo; o[1] = hi;
    }
  }
}

// ---------- fallback-path kernels ----------
__global__ void finalize_kernel(const float* __restrict__ row_sum, const float* __restrict__ copyg,
                                float* __restrict__ sscale) {
  unsigned r = blockIdx.x * blockDim.x + threadIdx.x;
  if (r < M_ROWS) sscale[r] = (1.f - copyg[r]) / row_sum[r];
}

__global__ void scale_kernel(float4* __restrict__ out, const float* __restrict__ sscale) {
  const unsigned total = M_ROWS * (N_VOCAB / 4);
  unsigned stride = gridDim.x * blockDim.x;
  for (unsigned i = blockIdx.x * blockDim.x + threadIdx.x; i < total; i += stride) {
    unsigned r = i / (N_VOCAB / 4);
    unsigned c = i % (N_VOCAB / 4);
    float s = sscale[r];
    float4 v = out[(size_t)r * (OUT_PITCH / 4) + c];
    v.x *= s; v.y *= s; v.z *= s; v.w *= s;
    out[(size_t)r * (OUT_PITCH / 4) + c] = v;
  }
}

// ---------- K4: copy branch scatter ----------
__global__ void copyprob_kernel(const float* __restrict__ attn, const int* __restrict__ src_ids,
                                const float* __restrict__ copyg, float* __restrict__ out) {
  unsigned r = blockIdx.x;
  unsigned tid = threadIdx.x;
  __shared__ float cp[CV_DIM];
  for (unsigned v = tid; v < CV_DIM; v += 128) cp[v] = 0.f;
  __syncthreads();
  unsigned batch = r >> 7;
  float g = copyg[r];
  for (unsigned s = tid; s < S_DIM; s += 128) {
    float a = attn[(size_t)r * S_DIM + s] * g;
    atomicAdd(&cp[src_ids[batch * S_DIM + s]], a);
  }
  __syncthreads();
  for (unsigned v = tid; v < CV_DIM; v += 128)
    out[(size_t)r * OUT_PITCH + N_VOCAB + v] = cp[v];
}

extern "C" void kernel_launch(void* const* d_in, const int* in_sizes, int n_in,
                              void* d_out, int out_size, void* d_ws, size_t ws_size,
                              hipStream_t stream) {
  const float* hidden    = (const float*)d_in[0];
  const float* copy_attn = (const float*)d_in[1];
  const float* src_map   = (const float*)d_in[2];
  const float* W         = (const float*)d_in[3];
  const float* bias      = (const float*)d_in[4];
  const float* w_copy    = (const float*)d_in[5];
  const float* b_copy    = (const float*)d_in[6];
  float* out = (float*)d_out;

  char* ws = (char*)d_ws;
  unsigned char* W8 = (unsigned char*)(ws + W8_OFF);
  unsigned char* H8 = (unsigned char*)(ws + H8_OFF);
  float* copyg   = (float*)(ws + COPYG_OFF);
  float* row_sum = (float*)(ws + RSUM_OFF);
  float* sscale  = (float*)(ws + SSCALE_OFF);
  int*   src_ids = (int*)(ws + SRCID_OFF);
  unsigned short* Eb = (unsigned short*)(ws + EB_OFF);

  const bool bf16_path = (ws_size >= WS_NEED);

  cvt8_kernel<<<2048, 256, 0, stream>>>((const float4*)W, (unsigned*)W8,
                                        (unsigned)(N_VOCAB * K_DIM / 4));
  copygate_cvt_kernel<<<M_ROWS / 4, 256, 0, stream>>>(hidden, w_copy, b_copy, copyg, H8);
  srcids_kernel<<<(32 * S_DIM) / 4, 256, 0, stream>>>(src_map, src_ids);

  // main GEMM: 16 x 250 tiles of 256x128, 512 threads, 2 blocks/CU
  if (bf16_path) {
    gemm_exp_kernel<1><<<(M_ROWS / 256) * (N_VOCAB / 128), 512, 0, stream>>>(
        H8, W8, bias, out, Eb, row_sum);
    norm_scale_kernel<<<M_ROWS, 256, 0, stream>>>(Eb, copyg, out);
  } else {
    hipMemsetAsync(row_sum, 0, M_ROWS * sizeof(float), stream);
    gemm_exp_kernel<0><<<(M_ROWS / 256) * (N_VOCAB / 128), 512, 0, stream>>>(
        H8, W8, bias, out, Eb, row_sum);
    finalize_kernel<<<(M_ROWS + 255) / 256, 256, 0, stream>>>(row_sum, copyg, sscale);
    scale_kernel<<<4096, 256, 0, stream>>>((float4*)out, sscale);
  }

  copyprob_kernel<<<M_ROWS, 128, 0, stream>>>(copy_attn, src_ids, copyg, out);
}